// Round 15
// baseline (174.673 us; speedup 1.0000x reference)
//
#include <hip/hip_runtime.h>
#include <math.h>

#define HH 96
#define WW 96
#define CC 64
#define NH 4
#define HD 16
#define KS 13
#define KK (KS*KS)
#define NTOK (HH*WW)

// ---------------- DPP cross-lane add (pure VALU, no LDS pipe) ---------------
// ctrl 0xB1 = quad_perm(1,0,3,2)  -> xor1 within quad
// ctrl 0x4E = quad_perm(2,3,0,1)  -> xor2 within quad
// ctrl 0x124 = row_ror:4, 0x128 = row_ror:8 (full-group sums: direction moot)
// ctrl 0x141 = row_half_mirror (valid when quads already uniform)
template<int CTRL>
__device__ __forceinline__ float dpp_add(float p) {
    int t = __builtin_amdgcn_update_dpp(0, __float_as_int(p), CTRL, 0xF, 0xF, true);
    return p + __int_as_float(t);
}

__device__ __forceinline__ float dpp_reduce8(float p) {
    p = dpp_add<0xB1>(p);
    p = dpp_add<0x4E>(p);
    p = dpp_add<0x141>(p);
    return p;
}

// In-place LayerNorm of a 32-token tile stored TRANSPOSED in LDS: buf[ch][tok].
// 256 threads: 8 lanes per row, 8 channels per lane (8-aligned lane groups).
template<int PITCH>
__device__ __forceinline__ void ln_rows(float (*buf)[PITCH],
                                        const float* __restrict__ g,
                                        const float* __restrict__ b,
                                        int tid) {
    int r  = tid >> 3;
    int c0 = (tid & 7) * 8;
    float v[8];
    float s = 0.0f;
    #pragma unroll
    for (int j = 0; j < 8; j++) { v[j] = buf[c0 + j][r]; s += v[j]; }
    s = dpp_reduce8(s);
    float mu = s * (1.0f / 64.0f);
    float s2 = 0.0f;
    #pragma unroll
    for (int j = 0; j < 8; j++) { float d = v[j] - mu; s2 += d * d; }
    s2 = dpp_reduce8(s2);
    float inv = rsqrtf(s2 * (1.0f / 64.0f) + 1e-5f);
    #pragma unroll
    for (int j = 0; j < 8; j++)
        buf[c0 + j][r] = (v[j] - mu) * inv * g[c0 + j] + b[c0 + j];
}

// ---------------- Fused LN1 + qkv GEMM, v2 ----------------------------------
// Rebuilt on the v4-MLP pattern. Old: grid (288,3) -- each tile staged+LN'd 3x,
// 2 rows/thread, ~221 MB issued-L1. New: ONE block per 32-token tile (stage+LN
// once), 256 thr, each thread 4 rows x 6 cols (3 x float2 stride 64 = fc1's gg
// pattern). Issued-L1 ~110 MB (time tracks issued-L1 at ~15 TB/s per R8/R9/R10
// controlled pairs). gg=0 covers cols 0..63 = q section (scaled 0.25).
// Pitch 36: &Ast[k][4*tr] 16B-aligned -> broadcast ds_read_b128.
__global__ __launch_bounds__(256) void ln_gemm_kernel(const float* __restrict__ x,
                                                      const float* __restrict__ g,
                                                      const float* __restrict__ b,
                                                      const float* __restrict__ W,
                                                      const float* __restrict__ bias,
                                                      float* __restrict__ out) {
    __shared__ float Ast[64][36];
    const int t0 = blockIdx.x * 32;
    const int tid = threadIdx.x;
    const int tc = tid & 31;         // col pair: cols 2tc, 2tc+1 (+64, +128)
    const int tr = tid >> 5;         // row group 0..7: rows 4tr..4tr+3
    const int r0 = tr * 4;
    const int c2 = tc * 2;

    // stage x tile transposed: 512 float4s, 2 per thread, coalesced
    #pragma unroll
    for (int j = 0; j < 2; j++) {
        int idx = tid + 256 * j;
        float4 v = ((const float4*)x)[t0 * 16 + idx];
        int row = idx >> 4, cc = (idx & 15) * 4;
        Ast[cc][row] = v.x; Ast[cc + 1][row] = v.y;
        Ast[cc + 2][row] = v.z; Ast[cc + 3][row] = v.w;
    }
    __syncthreads();
    ln_rows<36>(Ast, g, b, tid);
    __syncthreads();

    float2 acc[4][3];                // [row][gg]
    #pragma unroll
    for (int gg = 0; gg < 3; gg++) {
        float2 bb = *(const float2*)&bias[c2 + gg * 64];
        #pragma unroll
        for (int i = 0; i < 4; i++) acc[i][gg] = bb;
    }
    #pragma unroll 4
    for (int k = 0; k < 64; k++) {
        float4 aa = *(const float4*)&Ast[k][r0];       // rows r0..r0+3
        float  ar[4] = {aa.x, aa.y, aa.z, aa.w};
        #pragma unroll
        for (int gg = 0; gg < 3; gg++) {
            float2 w = *(const float2*)&W[k * 192 + c2 + gg * 64];
            #pragma unroll
            for (int i = 0; i < 4; i++) {
                acc[i][gg].x += ar[i] * w.x; acc[i][gg].y += ar[i] * w.y;
            }
        }
    }
    #pragma unroll
    for (int i = 0; i < 4; i++) {    // q section (gg=0, cols 0..63): hd^-0.5
        acc[i][0].x *= 0.25f; acc[i][0].y *= 0.25f;
    }
    #pragma unroll
    for (int i = 0; i < 4; i++)
        #pragma unroll
        for (int gg = 0; gg < 3; gg++)
            *(float2*)&out[(t0 + r0 + i) * 192 + c2 + gg * 64] = acc[i][gg];
}

// ---------------- Neighborhood attention (unchanged from R8) ----------------
__global__ __launch_bounds__(256) void na_attn_kernel(const float* __restrict__ qkv,
                                                      const float* __restrict__ rpb,
                                                      float* __restrict__ out) {
    int wave = threadIdx.x >> 6;
    int lane = threadIdx.x & 63;
    int bid  = blockIdx.x;
    int swz  = (bid & 7) * 288 + (bid >> 3);   // bijective: 2304 % 8 == 0
    int y    = swz / 24;                       // spatial row
    int rem  = swz - y * 24;
    int gw   = rem >> 3;                       // dilation group (x % 3)
    int iw   = (rem & 7) * 4 + wave;           // group-col of this wave's token
    int token = y * WW + gw + 3 * iw;

    int head = lane >> 4;
    int slot = (lane >> 2) & 3;
    int l    = lane & 3;
    int co   = head * HD + l * 4;

    int gh = y % 3, ih = y / 3;
    int sh = ih - 6; sh = sh < 0 ? 0 : (sh > 19 ? 19 : sh);
    int sw = iw - 6; sw = sw < 0 ? 0 : (sw > 19 ? 19 : sw);

    float4 q4 = *(const float4*)&qkv[token * 192 + co];
    const float* bias_h = rpb + head * 625 + (sw - iw + 12);

    const int xpart = (gw + 3 * sw) * 192 + 64 + co + slot * 576;

    float4 acc = make_float4(0.f, 0.f, 0.f, 0.f);
    float s = 0.0f;

    for (int kh = 0; kh < KS; kh++) {
        int ny = gh + 3 * (sh + kh);
        const float* kp = qkv + ny * (WW * 192) + xpart;
        const float* bp = bias_h + (sh + kh - ih + 12) * 25;
        #pragma unroll
        for (int i = 0; i < 3; i++) {          // kw = 4*i + slot : 0..11
            float4 k4 = *(const float4*)(kp + i * 2304);
            float4 v4 = *(const float4*)(kp + i * 2304 + 64);
            float p = q4.x * k4.x + q4.y * k4.y + q4.z * k4.z + q4.w * k4.w;
            p = dpp_add<0xB1>(p);
            p = dpp_add<0x4E>(p);              // p = 16-dim dot (quad sum)
            float e = __expf(p + bp[4 * i + slot]);
            s += e;
            acc.x += e * v4.x; acc.y += e * v4.y; acc.z += e * v4.z; acc.w += e * v4.w;
        }
        if (slot == 0) {                        // tail kw = 12 (quad-uniform branch)
            float4 k4 = *(const float4*)(kp + 3 * 2304);
            float4 v4 = *(const float4*)(kp + 3 * 2304 + 64);
            float p = q4.x * k4.x + q4.y * k4.y + q4.z * k4.z + q4.w * k4.w;
            p = dpp_add<0xB1>(p);
            p = dpp_add<0x4E>(p);
            float e = __expf(p + bp[12]);
            s += e;
            acc.x += e * v4.x; acc.y += e * v4.y; acc.z += e * v4.z; acc.w += e * v4.w;
        }
    }

    s = dpp_add<0x128>(s);  s = dpp_add<0x124>(s);
    acc.x = dpp_add<0x128>(acc.x); acc.x = dpp_add<0x124>(acc.x);
    acc.y = dpp_add<0x128>(acc.y); acc.y = dpp_add<0x124>(acc.y);
    acc.z = dpp_add<0x128>(acc.z); acc.z = dpp_add<0x124>(acc.z);
    acc.w = dpp_add<0x128>(acc.w); acc.w = dpp_add<0x124>(acc.w);

    if (slot == 0) {
        float inv = 1.0f / s;
        *(float4*)&out[token * CC + co] =
            make_float4(acc.x * inv, acc.y * inv, acc.z * inv, acc.w * inv);
    }
}

// ---------------- Fused proj+resid -> LN2 -> fc1+gelu -> fc2+resid ----------
// v4 (reverted from v5: 144-block/512-thr single-round variant showed no gain;
// v4 was the best-total config). 32 tok/block, 256 thr, 4 rows x 2 cols.
__global__ __launch_bounds__(256) void mlp_fused_kernel(const float* __restrict__ attn_out,
                                                        const float* __restrict__ x,
                                                        const float* __restrict__ proj_w,
                                                        const float* __restrict__ proj_b,
                                                        const float* __restrict__ n2g,
                                                        const float* __restrict__ n2b,
                                                        const float* __restrict__ fc1_w,
                                                        const float* __restrict__ fc1_b,
                                                        const float* __restrict__ fc2_w,
                                                        const float* __restrict__ fc2_b,
                                                        float* __restrict__ out) {
    __shared__ float Ast[64][36];    // attn_out^T tile      (9.2 KB)
    __shared__ float X2T[64][36];    // x2^T -> h2^T          (9.2 KB)
    __shared__ float Hid[256][36];   // hidden^T              (36.9 KB)

    const int t0 = blockIdx.x * 32;
    const int tid = threadIdx.x;
    const int tc = tid & 31;         // col pair: cols 2tc, 2tc+1
    const int tr = tid >> 5;         // row group 0..7: rows 4tr..4tr+3
    const int r0 = tr * 4;
    const int c2 = tc * 2;

    // stage attn_out tile transposed: 512 float4s, 2 per thread, coalesced
    #pragma unroll
    for (int j = 0; j < 2; j++) {
        int idx = tid + 256 * j;                 // float4 index 0..511
        float4 v = ((const float4*)attn_out)[t0 * 16 + idx];
        int row = idx >> 4, cc = (idx & 15) * 4;
        Ast[cc][row] = v.x; Ast[cc + 1][row] = v.y;
        Ast[cc + 2][row] = v.z; Ast[cc + 3][row] = v.w;
    }
    __syncthreads();

    // ---- proj + residual(x): x2 rows r0..r0+3 (cols c2,c2+1) in a[4] ----
    float2 pb = *(const float2*)&proj_b[c2];
    float2 a[4] = {pb, pb, pb, pb};
    #pragma unroll 8
    for (int k = 0; k < 64; k++) {
        float4 aa = *(const float4*)&Ast[k][r0];     // rows r0..r0+3
        float  ar[4] = {aa.x, aa.y, aa.z, aa.w};
        float2 w = *(const float2*)&proj_w[k * 64 + c2];
        #pragma unroll
        for (int i = 0; i < 4; i++) {
            a[i].x += ar[i] * w.x; a[i].y += ar[i] * w.y;
        }
    }
    {
        #pragma unroll
        for (int i = 0; i < 4; i++) {
            float2 xr = *(const float2*)&x[(t0 + r0 + i) * 64 + c2];
            a[i].x += xr.x; a[i].y += xr.y;
        }
        *(float4*)&X2T[c2][r0] =
            make_float4(a[0].x, a[1].x, a[2].x, a[3].x);
        *(float4*)&X2T[c2 + 1][r0] =
            make_float4(a[0].y, a[1].y, a[2].y, a[3].y);
    }
    __syncthreads();

    // ---- LN2 in place on X2T (256 thr: 8 lanes/row, 8 ch/lane) ----
    ln_rows<36>(X2T, n2g, n2b, tid);
    __syncthreads();

    // ---- fc1 + gelu -> Hid. Thread: 4 rows x 8 cols (4 gg x float2) ----
    float2 h[4][4];                  // h[row][gg]
    #pragma unroll
    for (int gg = 0; gg < 4; gg++) {
        float2 bb = *(const float2*)&fc1_b[c2 + gg * 64];
        #pragma unroll
        for (int i = 0; i < 4; i++) h[i][gg] = bb;
    }
    #pragma unroll 4
    for (int k = 0; k < 64; k++) {
        float4 aa = *(const float4*)&X2T[k][r0];
        float  ar[4] = {aa.x, aa.y, aa.z, aa.w};
        #pragma unroll
        for (int gg = 0; gg < 4; gg++) {
            float2 w = *(const float2*)&fc1_w[k * 256 + c2 + gg * 64];
            #pragma unroll
            for (int i = 0; i < 4; i++) {
                h[i][gg].x += ar[i] * w.x; h[i][gg].y += ar[i] * w.y;
            }
        }
    }
    #define GELU1(v) v = 0.5f * v * (1.0f + erff(v * 0.70710678118f))
    #pragma unroll
    for (int i = 0; i < 4; i++)
        #pragma unroll
        for (int gg = 0; gg < 4; gg++) { GELU1(h[i][gg].x); GELU1(h[i][gg].y); }
    #undef GELU1
    #pragma unroll
    for (int gg = 0; gg < 4; gg++) {
        *(float4*)&Hid[c2 + gg * 64][r0] =
            make_float4(h[0][gg].x, h[1][gg].x, h[2][gg].x, h[3][gg].x);
        *(float4*)&Hid[c2 + 1 + gg * 64][r0] =
            make_float4(h[0][gg].y, h[1][gg].y, h[2][gg].y, h[3][gg].y);
    }
    __syncthreads();

    // ---- fc2 + residual(x2 from registers a[4]) ----
    float2 ob = *(const float2*)&fc2_b[c2];
    float2 o[4] = {ob, ob, ob, ob};
    #pragma unroll 8
    for (int k = 0; k < 256; k++) {
        float4 aa = *(const float4*)&Hid[k][r0];
        float  ar[4] = {aa.x, aa.y, aa.z, aa.w};
        float2 w = *(const float2*)&fc2_w[k * 64 + c2];
        #pragma unroll
        for (int i = 0; i < 4; i++) {
            o[i].x += ar[i] * w.x; o[i].y += ar[i] * w.y;
        }
    }
    #pragma unroll
    for (int i = 0; i < 4; i++) {
        o[i].x += a[i].x; o[i].y += a[i].y;
        *(float2*)&out[(t0 + r0 + i) * 64 + c2] = o[i];
    }
}

extern "C" void kernel_launch(void* const* d_in, const int* in_sizes, int n_in,
                              void* d_out, int out_size, void* d_ws, size_t ws_size,
                              hipStream_t stream) {
    const float* x       = (const float*)d_in[0];
    const float* norm1_g = (const float*)d_in[1];
    const float* norm1_b = (const float*)d_in[2];
    const float* qkv_w   = (const float*)d_in[3];
    const float* qkv_b   = (const float*)d_in[4];
    const float* rpb     = (const float*)d_in[5];
    const float* proj_w  = (const float*)d_in[6];
    const float* proj_b  = (const float*)d_in[7];
    const float* norm2_g = (const float*)d_in[8];
    const float* norm2_b = (const float*)d_in[9];
    const float* fc1_w   = (const float*)d_in[10];
    const float* fc1_b   = (const float*)d_in[11];
    const float* fc2_w   = (const float*)d_in[12];
    const float* fc2_b   = (const float*)d_in[13];
    float* out = (float*)d_out;

    float* ws = (float*)d_ws;
    float* qkv      = ws;                      // 9216*192
    float* attn_out = qkv + NTOK * 192;        // 9216*64

    dim3 blk(256);
    // 1. qkv = LN1(x) @ qkv_w + qkv_b  (one block per tile, all 192 cols)
    ln_gemm_kernel<<<NTOK / 32, blk, 0, stream>>>(x, norm1_g, norm1_b, qkv_w, qkv_b, qkv);
    // 2. neighborhood attention (1 token/wave; block = 4 window-sharing tokens)
    na_attn_kernel<<<NTOK / 4, blk, 0, stream>>>(qkv, rpb, attn_out);
    // 3. out = fused MLP (v4: 32 tok/block, 256 thr, 4 rows x 2 cols)
    mlp_fused_kernel<<<NTOK / 32, blk, 0, stream>>>(attn_out, x, proj_w, proj_b,
                                                    norm2_g, norm2_b, fc1_w, fc1_b,
                                                    fc2_w, fc2_b, out);
}

// Round 16
// 156.374 us; speedup vs baseline: 1.1170x; 1.1170x over previous
//
#include <hip/hip_runtime.h>
#include <math.h>

#define HH 96
#define WW 96
#define CC 64
#define NH 4
#define HD 16
#define KS 13
#define KK (KS*KS)
#define NTOK (HH*WW)

// ---------------- DPP cross-lane add (pure VALU, no LDS pipe) ---------------
// ctrl 0xB1 = quad_perm(1,0,3,2)  -> xor1 within quad
// ctrl 0x4E = quad_perm(2,3,0,1)  -> xor2 within quad
// ctrl 0x124 = row_ror:4, 0x128 = row_ror:8 (full-group sums: direction moot)
// ctrl 0x141 = row_half_mirror (valid when quads already uniform)
template<int CTRL>
__device__ __forceinline__ float dpp_add(float p) {
    int t = __builtin_amdgcn_update_dpp(0, __float_as_int(p), CTRL, 0xF, 0xF, true);
    return p + __int_as_float(t);
}

__device__ __forceinline__ float dpp_reduce8(float p) {
    p = dpp_add<0xB1>(p);
    p = dpp_add<0x4E>(p);
    p = dpp_add<0x141>(p);
    return p;
}

// In-place LayerNorm of a 32-token tile stored TRANSPOSED in LDS: buf[ch][tok].
// 256 threads: 8 lanes per row, 8 channels per lane (8-aligned lane groups).
template<int PITCH>
__device__ __forceinline__ void ln_rows(float (*buf)[PITCH],
                                        const float* __restrict__ g,
                                        const float* __restrict__ b,
                                        int tid) {
    int r  = tid >> 3;
    int c0 = (tid & 7) * 8;
    float v[8];
    float s = 0.0f;
    #pragma unroll
    for (int j = 0; j < 8; j++) { v[j] = buf[c0 + j][r]; s += v[j]; }
    s = dpp_reduce8(s);
    float mu = s * (1.0f / 64.0f);
    float s2 = 0.0f;
    #pragma unroll
    for (int j = 0; j < 8; j++) { float d = v[j] - mu; s2 += d * d; }
    s2 = dpp_reduce8(s2);
    float inv = rsqrtf(s2 * (1.0f / 64.0f) + 1e-5f);
    #pragma unroll
    for (int j = 0; j < 8; j++)
        buf[c0 + j][r] = (v[j] - mu) * inv * g[c0 + j] + b[c0 + j];
}

// ---------------- Fused LN1 + qkv GEMM (v2, unchanged from R15) -------------
__global__ __launch_bounds__(256) void ln_gemm_kernel(const float* __restrict__ x,
                                                      const float* __restrict__ g,
                                                      const float* __restrict__ b,
                                                      const float* __restrict__ W,
                                                      const float* __restrict__ bias,
                                                      float* __restrict__ out) {
    __shared__ float Ast[64][36];
    const int t0 = blockIdx.x * 32;
    const int tid = threadIdx.x;
    const int tc = tid & 31;
    const int tr = tid >> 5;
    const int r0 = tr * 4;
    const int c2 = tc * 2;

    #pragma unroll
    for (int j = 0; j < 2; j++) {
        int idx = tid + 256 * j;
        float4 v = ((const float4*)x)[t0 * 16 + idx];
        int row = idx >> 4, cc = (idx & 15) * 4;
        Ast[cc][row] = v.x; Ast[cc + 1][row] = v.y;
        Ast[cc + 2][row] = v.z; Ast[cc + 3][row] = v.w;
    }
    __syncthreads();
    ln_rows<36>(Ast, g, b, tid);
    __syncthreads();

    float2 acc[4][3];
    #pragma unroll
    for (int gg = 0; gg < 3; gg++) {
        float2 bb = *(const float2*)&bias[c2 + gg * 64];
        #pragma unroll
        for (int i = 0; i < 4; i++) acc[i][gg] = bb;
    }
    #pragma unroll 4
    for (int k = 0; k < 64; k++) {
        float4 aa = *(const float4*)&Ast[k][r0];
        float  ar[4] = {aa.x, aa.y, aa.z, aa.w};
        #pragma unroll
        for (int gg = 0; gg < 3; gg++) {
            float2 w = *(const float2*)&W[k * 192 + c2 + gg * 64];
            #pragma unroll
            for (int i = 0; i < 4; i++) {
                acc[i][gg].x += ar[i] * w.x; acc[i][gg].y += ar[i] * w.y;
            }
        }
    }
    #pragma unroll
    for (int i = 0; i < 4; i++) {
        acc[i][0].x *= 0.25f; acc[i][0].y *= 0.25f;
    }
    #pragma unroll
    for (int i = 0; i < 4; i++)
        #pragma unroll
        for (int gg = 0; gg < 3; gg++)
            *(float2*)&out[(t0 + r0 + i) * 192 + c2 + gg * 64] = acc[i][gg];
}

// ---------------- Neighborhood attention: LDS-staged K/V window -------------
// Diagnosis (R15): attn is L1-throughput-bound -- 9216 waves x 86 x 1KB loads
// = 811 MB issued-L1 for a 4.7 MB unique K/V set (172x amplification).
// Fix: block = 4 window-sharing tokens (R8 composition: same y, same dilation
// group gw, iw0..iw0+3). ny rows and the <=16-col union window are BLOCK-
// UNIFORM, so per kh-row the block cooperatively stages 16 cols x 128 floats
// (k+v, 8 KB) to LDS once; all 4 waves read fragments from LDS (LDS pipe,
// not L1). Issued-L1 drops 3.4x to ~240 MB. Compute: R8's slot-parallel loop
// (col j = 4i+slot, 4 iters/kh) + R6's proven union-window mask
// (rel clamp 24, bias=-1e30 for out-of-window -> exp=0 exact).
// Pitch 132 (528 B = 33x16): float4-aligned, col stride = 4 banks.
__global__ __launch_bounds__(256) void na_attn_kernel(const float* __restrict__ qkv,
                                                      const float* __restrict__ rpb,
                                                      float* __restrict__ out) {
    __shared__ float KV[16][132];   // col j: k at [j][0..63], v at [j][64..127]

    int wave = threadIdx.x >> 6;
    int lane = threadIdx.x & 63;
    int bid  = blockIdx.x;
    int swz  = (bid & 7) * 288 + (bid >> 3);   // XCD swizzle (2304 % 8 == 0)
    int y    = swz / 24;
    int rem  = swz - y * 24;
    int gw   = rem >> 3;                       // dilation group (x % 3)
    int iw0  = (rem & 7) * 4;                  // first token's group-col
    int iw   = iw0 + wave;                     // this wave's token
    int token = y * WW + gw + 3 * iw;

    int head = lane >> 4;
    int slot = (lane >> 2) & 3;
    int l    = lane & 3;
    int co   = head * HD + l * 4;

    int gh = y % 3, ih = y / 3;
    int sh = ih - 6; sh = sh < 0 ? 0 : (sh > 19 ? 19 : sh);
    int sw = iw - 6; sw = sw < 0 ? 0 : (sw > 19 ? 19 : sw);
    int cbase = iw0 - 6; cbase = cbase < 0 ? 0 : (cbase > 19 ? 19 : cbase);

    float4 q4 = *(const float4*)&qkv[token * 192 + co];
    const float* bias_h = rpb + head * 625;

    float4 acc = make_float4(0.f, 0.f, 0.f, 0.f);
    float s = 0.0f;

    for (int kh = 0; kh < KS; kh++) {
        int ny = gh + 3 * (sh + kh);                   // block-uniform
        int rh = sh + kh - ih + 12;
        const float* rowbase = qkv + (ny * WW + gw) * 192 + 64;

        __syncthreads();                               // protect prior reads
        // stage 16 cols x 128 floats = 512 float4s; 2 per thread, coalesced
        #pragma unroll
        for (int j2 = 0; j2 < 2; j2++) {
            int F   = threadIdx.x + 256 * j2;          // 0..511
            int col = F >> 5;                          // 0..15
            int o   = (F & 31) * 4;                    // 0..124
            int c   = cbase + col;
            int cl  = c > 31 ? 31 : c;                 // in-bounds (masked later)
            float4 v = *(const float4*)(rowbase + cl * 576 + o);
            *(float4*)&KV[col][o] = v;
        }
        __syncthreads();

        const float* brow = bias_h + rh * 25;
        #pragma unroll
        for (int i = 0; i < 4; i++) {                  // col j = 4i + slot
            int j = 4 * i + slot;
            float4 k4 = *(const float4*)&KV[j][co];
            float4 v4 = *(const float4*)&KV[j][64 + co];
            int c = cbase + j;
            int rel = c - iw + 12;                     // >= 0 provable
            float bias = brow[rel > 24 ? 24 : rel];
            unsigned kw = (unsigned)(c - sw);
            bias = (kw <= 12u) ? bias : -1e30f;        // mask -> exp = 0
            float p = q4.x * k4.x + q4.y * k4.y + q4.z * k4.z + q4.w * k4.w;
            p = dpp_add<0xB1>(p);
            p = dpp_add<0x4E>(p);                      // 16-dim dot (quad sum)
            float e = __expf(p + bias);
            s += e;
            acc.x += e * v4.x; acc.y += e * v4.y; acc.z += e * v4.z; acc.w += e * v4.w;
        }
    }

    // combine the 4 slot partials (lane bits 2..3)
    s = dpp_add<0x128>(s);  s = dpp_add<0x124>(s);
    acc.x = dpp_add<0x128>(acc.x); acc.x = dpp_add<0x124>(acc.x);
    acc.y = dpp_add<0x128>(acc.y); acc.y = dpp_add<0x124>(acc.y);
    acc.z = dpp_add<0x128>(acc.z); acc.z = dpp_add<0x124>(acc.z);
    acc.w = dpp_add<0x128>(acc.w); acc.w = dpp_add<0x124>(acc.w);

    if (slot == 0) {
        float inv = 1.0f / s;
        *(float4*)&out[token * CC + co] =
            make_float4(acc.x * inv, acc.y * inv, acc.z * inv, acc.w * inv);
    }
}

// ---------------- Fused proj+resid -> LN2 -> fc1+gelu -> fc2+resid ----------
// v4 (best-total config). 32 tok/block, 256 thr, 4 rows x 2 cols.
__global__ __launch_bounds__(256) void mlp_fused_kernel(const float* __restrict__ attn_out,
                                                        const float* __restrict__ x,
                                                        const float* __restrict__ proj_w,
                                                        const float* __restrict__ proj_b,
                                                        const float* __restrict__ n2g,
                                                        const float* __restrict__ n2b,
                                                        const float* __restrict__ fc1_w,
                                                        const float* __restrict__ fc1_b,
                                                        const float* __restrict__ fc2_w,
                                                        const float* __restrict__ fc2_b,
                                                        float* __restrict__ out) {
    __shared__ float Ast[64][36];
    __shared__ float X2T[64][36];
    __shared__ float Hid[256][36];

    const int t0 = blockIdx.x * 32;
    const int tid = threadIdx.x;
    const int tc = tid & 31;
    const int tr = tid >> 5;
    const int r0 = tr * 4;
    const int c2 = tc * 2;

    #pragma unroll
    for (int j = 0; j < 2; j++) {
        int idx = tid + 256 * j;
        float4 v = ((const float4*)attn_out)[t0 * 16 + idx];
        int row = idx >> 4, cc = (idx & 15) * 4;
        Ast[cc][row] = v.x; Ast[cc + 1][row] = v.y;
        Ast[cc + 2][row] = v.z; Ast[cc + 3][row] = v.w;
    }
    __syncthreads();

    float2 pb = *(const float2*)&proj_b[c2];
    float2 a[4] = {pb, pb, pb, pb};
    #pragma unroll 8
    for (int k = 0; k < 64; k++) {
        float4 aa = *(const float4*)&Ast[k][r0];
        float  ar[4] = {aa.x, aa.y, aa.z, aa.w};
        float2 w = *(const float2*)&proj_w[k * 64 + c2];
        #pragma unroll
        for (int i = 0; i < 4; i++) {
            a[i].x += ar[i] * w.x; a[i].y += ar[i] * w.y;
        }
    }
    {
        #pragma unroll
        for (int i = 0; i < 4; i++) {
            float2 xr = *(const float2*)&x[(t0 + r0 + i) * 64 + c2];
            a[i].x += xr.x; a[i].y += xr.y;
        }
        *(float4*)&X2T[c2][r0] =
            make_float4(a[0].x, a[1].x, a[2].x, a[3].x);
        *(float4*)&X2T[c2 + 1][r0] =
            make_float4(a[0].y, a[1].y, a[2].y, a[3].y);
    }
    __syncthreads();

    ln_rows<36>(X2T, n2g, n2b, tid);
    __syncthreads();

    float2 h[4][4];
    #pragma unroll
    for (int gg = 0; gg < 4; gg++) {
        float2 bb = *(const float2*)&fc1_b[c2 + gg * 64];
        #pragma unroll
        for (int i = 0; i < 4; i++) h[i][gg] = bb;
    }
    #pragma unroll 4
    for (int k = 0; k < 64; k++) {
        float4 aa = *(const float4*)&X2T[k][r0];
        float  ar[4] = {aa.x, aa.y, aa.z, aa.w};
        #pragma unroll
        for (int gg = 0; gg < 4; gg++) {
            float2 w = *(const float2*)&fc1_w[k * 256 + c2 + gg * 64];
            #pragma unroll
            for (int i = 0; i < 4; i++) {
                h[i][gg].x += ar[i] * w.x; h[i][gg].y += ar[i] * w.y;
            }
        }
    }
    #define GELU1(v) v = 0.5f * v * (1.0f + erff(v * 0.70710678118f))
    #pragma unroll
    for (int i = 0; i < 4; i++)
        #pragma unroll
        for (int gg = 0; gg < 4; gg++) { GELU1(h[i][gg].x); GELU1(h[i][gg].y); }
    #undef GELU1
    #pragma unroll
    for (int gg = 0; gg < 4; gg++) {
        *(float4*)&Hid[c2 + gg * 64][r0] =
            make_float4(h[0][gg].x, h[1][gg].x, h[2][gg].x, h[3][gg].x);
        *(float4*)&Hid[c2 + 1 + gg * 64][r0] =
            make_float4(h[0][gg].y, h[1][gg].y, h[2][gg].y, h[3][gg].y);
    }
    __syncthreads();

    float2 ob = *(const float2*)&fc2_b[c2];
    float2 o[4] = {ob, ob, ob, ob};
    #pragma unroll 8
    for (int k = 0; k < 256; k++) {
        float4 aa = *(const float4*)&Hid[k][r0];
        float  ar[4] = {aa.x, aa.y, aa.z, aa.w};
        float2 w = *(const float2*)&fc2_w[k * 64 + c2];
        #pragma unroll
        for (int i = 0; i < 4; i++) {
            o[i].x += ar[i] * w.x; o[i].y += ar[i] * w.y;
        }
    }
    #pragma unroll
    for (int i = 0; i < 4; i++) {
        o[i].x += a[i].x; o[i].y += a[i].y;
        *(float2*)&out[(t0 + r0 + i) * 64 + c2] = o[i];
    }
}

extern "C" void kernel_launch(void* const* d_in, const int* in_sizes, int n_in,
                              void* d_out, int out_size, void* d_ws, size_t ws_size,
                              hipStream_t stream) {
    const float* x       = (const float*)d_in[0];
    const float* norm1_g = (const float*)d_in[1];
    const float* norm1_b = (const float*)d_in[2];
    const float* qkv_w   = (const float*)d_in[3];
    const float* qkv_b   = (const float*)d_in[4];
    const float* rpb     = (const float*)d_in[5];
    const float* proj_w  = (const float*)d_in[6];
    const float* proj_b  = (const float*)d_in[7];
    const float* norm2_g = (const float*)d_in[8];
    const float* norm2_b = (const float*)d_in[9];
    const float* fc1_w   = (const float*)d_in[10];
    const float* fc1_b   = (const float*)d_in[11];
    const float* fc2_w   = (const float*)d_in[12];
    const float* fc2_b   = (const float*)d_in[13];
    float* out = (float*)d_out;

    float* ws = (float*)d_ws;
    float* qkv      = ws;                      // 9216*192
    float* attn_out = qkv + NTOK * 192;        // 9216*64

    dim3 blk(256);
    // 1. qkv = LN1(x) @ qkv_w + qkv_b  (one block per tile, all 192 cols)
    ln_gemm_kernel<<<NTOK / 32, blk, 0, stream>>>(x, norm1_g, norm1_b, qkv_w, qkv_b, qkv);
    // 2. neighborhood attention (LDS-staged K/V window; 4 tokens/block)
    na_attn_kernel<<<NTOK / 16, blk, 0, stream>>>(qkv, rpb, attn_out);
    // 3. out = fused MLP (v4: 32 tok/block, 256 thr, 4 rows x 2 cols)
    mlp_fused_kernel<<<NTOK / 32, blk, 0, stream>>>(attn_out, x, proj_w, proj_b,
                                                    norm2_g, norm2_b, fc1_w, fc1_b,
                                                    fc2_w, fc2_b, out);
}

// Round 17
// 156.132 us; speedup vs baseline: 1.1188x; 1.0015x over previous
//
#include <hip/hip_runtime.h>
#include <math.h>

#define HH 96
#define WW 96
#define CC 64
#define NH 4
#define HD 16
#define KS 13
#define KK (KS*KS)
#define NTOK (HH*WW)

// ---------------- DPP cross-lane add (pure VALU, no LDS pipe) ---------------
// ctrl 0xB1 = quad_perm(1,0,3,2)  -> xor1 within quad
// ctrl 0x4E = quad_perm(2,3,0,1)  -> xor2 within quad
// ctrl 0x124 = row_ror:4, 0x128 = row_ror:8 (full-group sums: direction moot)
// ctrl 0x141 = row_half_mirror (valid when quads already uniform)
template<int CTRL>
__device__ __forceinline__ float dpp_add(float p) {
    int t = __builtin_amdgcn_update_dpp(0, __float_as_int(p), CTRL, 0xF, 0xF, true);
    return p + __int_as_float(t);
}

__device__ __forceinline__ float dpp_reduce8(float p) {
    p = dpp_add<0xB1>(p);
    p = dpp_add<0x4E>(p);
    p = dpp_add<0x141>(p);
    return p;
}

// In-place LayerNorm of a 32-token tile stored TRANSPOSED in LDS: buf[ch][tok].
// 256 threads: 8 lanes per row, 8 channels per lane (8-aligned lane groups).
template<int PITCH>
__device__ __forceinline__ void ln_rows(float (*buf)[PITCH],
                                        const float* __restrict__ g,
                                        const float* __restrict__ b,
                                        int tid) {
    int r  = tid >> 3;
    int c0 = (tid & 7) * 8;
    float v[8];
    float s = 0.0f;
    #pragma unroll
    for (int j = 0; j < 8; j++) { v[j] = buf[c0 + j][r]; s += v[j]; }
    s = dpp_reduce8(s);
    float mu = s * (1.0f / 64.0f);
    float s2 = 0.0f;
    #pragma unroll
    for (int j = 0; j < 8; j++) { float d = v[j] - mu; s2 += d * d; }
    s2 = dpp_reduce8(s2);
    float inv = rsqrtf(s2 * (1.0f / 64.0f) + 1e-5f);
    #pragma unroll
    for (int j = 0; j < 8; j++)
        buf[c0 + j][r] = (v[j] - mu) * inv * g[c0 + j] + b[c0 + j];
}

// ---------------- Fused LN1 + qkv GEMM (v2, unchanged from R16) -------------
__global__ __launch_bounds__(256) void ln_gemm_kernel(const float* __restrict__ x,
                                                      const float* __restrict__ g,
                                                      const float* __restrict__ b,
                                                      const float* __restrict__ W,
                                                      const float* __restrict__ bias,
                                                      float* __restrict__ out) {
    __shared__ float Ast[64][36];
    const int t0 = blockIdx.x * 32;
    const int tid = threadIdx.x;
    const int tc = tid & 31;
    const int tr = tid >> 5;
    const int r0 = tr * 4;
    const int c2 = tc * 2;

    #pragma unroll
    for (int j = 0; j < 2; j++) {
        int idx = tid + 256 * j;
        float4 v = ((const float4*)x)[t0 * 16 + idx];
        int row = idx >> 4, cc = (idx & 15) * 4;
        Ast[cc][row] = v.x; Ast[cc + 1][row] = v.y;
        Ast[cc + 2][row] = v.z; Ast[cc + 3][row] = v.w;
    }
    __syncthreads();
    ln_rows<36>(Ast, g, b, tid);
    __syncthreads();

    float2 acc[4][3];
    #pragma unroll
    for (int gg = 0; gg < 3; gg++) {
        float2 bb = *(const float2*)&bias[c2 + gg * 64];
        #pragma unroll
        for (int i = 0; i < 4; i++) acc[i][gg] = bb;
    }
    #pragma unroll 4
    for (int k = 0; k < 64; k++) {
        float4 aa = *(const float4*)&Ast[k][r0];
        float  ar[4] = {aa.x, aa.y, aa.z, aa.w};
        #pragma unroll
        for (int gg = 0; gg < 3; gg++) {
            float2 w = *(const float2*)&W[k * 192 + c2 + gg * 64];
            #pragma unroll
            for (int i = 0; i < 4; i++) {
                acc[i][gg].x += ar[i] * w.x; acc[i][gg].y += ar[i] * w.y;
            }
        }
    }
    #pragma unroll
    for (int i = 0; i < 4; i++) {
        acc[i][0].x *= 0.25f; acc[i][0].y *= 0.25f;
    }
    #pragma unroll
    for (int i = 0; i < 4; i++)
        #pragma unroll
        for (int gg = 0; gg < 3; gg++)
            *(float2*)&out[(t0 + r0 + i) * 192 + c2 + gg * 64] = acc[i][gg];
}

// ---------------- Neighborhood attention: double-buffered LDS K/V -----------
// R16 proved attn was L1-throughput-bound; LDS staging bought ~18 us. This
// round removes the remaining serialization: the {stage -> sync -> compute}
// loop paid 26 barriers/block and exposed each 8 KB stage's global latency
// on the critical path. Double buffer KV[2]: issue stage of row kh+1 into
// buf[cur^1] BEFORE computing row kh from buf[cur]; ONE barrier per iter
// (14 total). Global-load latency of kh+1 hides under compute of kh.
// The single end-of-iter barrier provides both hazards: all waves done
// reading buf[cur] before next iter overwrites it, and stage writes to
// buf[cur^1] land before next iter reads them. Arithmetic order unchanged.
__global__ __launch_bounds__(256) void na_attn_kernel(const float* __restrict__ qkv,
                                                      const float* __restrict__ rpb,
                                                      float* __restrict__ out) {
    __shared__ float KV[2][16][132];  // col j: k at [j][0..63], v at [j][64..127]

    int wave = threadIdx.x >> 6;
    int lane = threadIdx.x & 63;
    int bid  = blockIdx.x;
    int swz  = (bid & 7) * 288 + (bid >> 3);   // XCD swizzle (2304 % 8 == 0)
    int y    = swz / 24;
    int rem  = swz - y * 24;
    int gw   = rem >> 3;                       // dilation group (x % 3)
    int iw0  = (rem & 7) * 4;                  // first token's group-col
    int iw   = iw0 + wave;                     // this wave's token
    int token = y * WW + gw + 3 * iw;

    int head = lane >> 4;
    int slot = (lane >> 2) & 3;
    int l    = lane & 3;
    int co   = head * HD + l * 4;

    int gh = y % 3, ih = y / 3;
    int sh = ih - 6; sh = sh < 0 ? 0 : (sh > 19 ? 19 : sh);
    int sw = iw - 6; sw = sw < 0 ? 0 : (sw > 19 ? 19 : sw);
    int cbase = iw0 - 6; cbase = cbase < 0 ? 0 : (cbase > 19 ? 19 : cbase);

    float4 q4 = *(const float4*)&qkv[token * 192 + co];
    const float* bias_h = rpb + head * 625;

    // per-thread staging indices (constant across kh)
    const int sF0  = threadIdx.x;              // float4 index 0..255
    const int sF1  = threadIdx.x + 256;        // 256..511
    const int col0 = sF0 >> 5, o0 = (sF0 & 31) * 4;
    const int col1 = sF1 >> 5, o1 = (sF1 & 31) * 4;
    int c0g = cbase + col0; c0g = c0g > 31 ? 31 : c0g;
    int c1g = cbase + col1; c1g = c1g > 31 ? 31 : c1g;
    const int base_off = gw * 192 + 64;        // + ny*WW*192 per row

    float4 acc = make_float4(0.f, 0.f, 0.f, 0.f);
    float s = 0.0f;

    // prologue: stage kh = 0 into buf 0
    {
        const float* rowbase = qkv + (gh + 3 * sh) * (WW * 192) + base_off;
        *(float4*)&KV[0][col0][o0] = *(const float4*)(rowbase + c0g * 576 + o0);
        *(float4*)&KV[0][col1][o1] = *(const float4*)(rowbase + c1g * 576 + o1);
    }
    __syncthreads();

    for (int kh = 0; kh < KS; kh++) {
        int cur = kh & 1;
        // issue next-row stage first (latency hides under compute below)
        if (kh < KS - 1) {
            const float* rowbase = qkv + (gh + 3 * (sh + kh + 1)) * (WW * 192) + base_off;
            *(float4*)&KV[cur ^ 1][col0][o0] = *(const float4*)(rowbase + c0g * 576 + o0);
            *(float4*)&KV[cur ^ 1][col1][o1] = *(const float4*)(rowbase + c1g * 576 + o1);
        }

        int rh = sh + kh - ih + 12;
        const float* brow = bias_h + rh * 25;
        #pragma unroll
        for (int i = 0; i < 4; i++) {                  // col j = 4i + slot
            int j = 4 * i + slot;
            float4 k4 = *(const float4*)&KV[cur][j][co];
            float4 v4 = *(const float4*)&KV[cur][j][64 + co];
            int c = cbase + j;
            int rel = c - iw + 12;                     // >= 0 provable
            float bias = brow[rel > 24 ? 24 : rel];
            unsigned kw = (unsigned)(c - sw);
            bias = (kw <= 12u) ? bias : -1e30f;        // mask -> exp = 0
            float p = q4.x * k4.x + q4.y * k4.y + q4.z * k4.z + q4.w * k4.w;
            p = dpp_add<0xB1>(p);
            p = dpp_add<0x4E>(p);                      // 16-dim dot (quad sum)
            float e = __expf(p + bias);
            s += e;
            acc.x += e * v4.x; acc.y += e * v4.y; acc.z += e * v4.z; acc.w += e * v4.w;
        }
        __syncthreads();                               // single barrier per kh
    }

    // combine the 4 slot partials (lane bits 2..3)
    s = dpp_add<0x128>(s);  s = dpp_add<0x124>(s);
    acc.x = dpp_add<0x128>(acc.x); acc.x = dpp_add<0x124>(acc.x);
    acc.y = dpp_add<0x128>(acc.y); acc.y = dpp_add<0x124>(acc.y);
    acc.z = dpp_add<0x128>(acc.z); acc.z = dpp_add<0x124>(acc.z);
    acc.w = dpp_add<0x128>(acc.w); acc.w = dpp_add<0x124>(acc.w);

    if (slot == 0) {
        float inv = 1.0f / s;
        *(float4*)&out[token * CC + co] =
            make_float4(acc.x * inv, acc.y * inv, acc.z * inv, acc.w * inv);
    }
}

// ---------------- Fused proj+resid -> LN2 -> fc1+gelu -> fc2+resid ----------
// v4 (best-total config). 32 tok/block, 256 thr, 4 rows x 2 cols.
__global__ __launch_bounds__(256) void mlp_fused_kernel(const float* __restrict__ attn_out,
                                                        const float* __restrict__ x,
                                                        const float* __restrict__ proj_w,
                                                        const float* __restrict__ proj_b,
                                                        const float* __restrict__ n2g,
                                                        const float* __restrict__ n2b,
                                                        const float* __restrict__ fc1_w,
                                                        const float* __restrict__ fc1_b,
                                                        const float* __restrict__ fc2_w,
                                                        const float* __restrict__ fc2_b,
                                                        float* __restrict__ out) {
    __shared__ float Ast[64][36];
    __shared__ float X2T[64][36];
    __shared__ float Hid[256][36];

    const int t0 = blockIdx.x * 32;
    const int tid = threadIdx.x;
    const int tc = tid & 31;
    const int tr = tid >> 5;
    const int r0 = tr * 4;
    const int c2 = tc * 2;

    #pragma unroll
    for (int j = 0; j < 2; j++) {
        int idx = tid + 256 * j;
        float4 v = ((const float4*)attn_out)[t0 * 16 + idx];
        int row = idx >> 4, cc = (idx & 15) * 4;
        Ast[cc][row] = v.x; Ast[cc + 1][row] = v.y;
        Ast[cc + 2][row] = v.z; Ast[cc + 3][row] = v.w;
    }
    __syncthreads();

    float2 pb = *(const float2*)&proj_b[c2];
    float2 a[4] = {pb, pb, pb, pb};
    #pragma unroll 8
    for (int k = 0; k < 64; k++) {
        float4 aa = *(const float4*)&Ast[k][r0];
        float  ar[4] = {aa.x, aa.y, aa.z, aa.w};
        float2 w = *(const float2*)&proj_w[k * 64 + c2];
        #pragma unroll
        for (int i = 0; i < 4; i++) {
            a[i].x += ar[i] * w.x; a[i].y += ar[i] * w.y;
        }
    }
    {
        #pragma unroll
        for (int i = 0; i < 4; i++) {
            float2 xr = *(const float2*)&x[(t0 + r0 + i) * 64 + c2];
            a[i].x += xr.x; a[i].y += xr.y;
        }
        *(float4*)&X2T[c2][r0] =
            make_float4(a[0].x, a[1].x, a[2].x, a[3].x);
        *(float4*)&X2T[c2 + 1][r0] =
            make_float4(a[0].y, a[1].y, a[2].y, a[3].y);
    }
    __syncthreads();

    ln_rows<36>(X2T, n2g, n2b, tid);
    __syncthreads();

    float2 h[4][4];
    #pragma unroll
    for (int gg = 0; gg < 4; gg++) {
        float2 bb = *(const float2*)&fc1_b[c2 + gg * 64];
        #pragma unroll
        for (int i = 0; i < 4; i++) h[i][gg] = bb;
    }
    #pragma unroll 4
    for (int k = 0; k < 64; k++) {
        float4 aa = *(const float4*)&X2T[k][r0];
        float  ar[4] = {aa.x, aa.y, aa.z, aa.w};
        #pragma unroll
        for (int gg = 0; gg < 4; gg++) {
            float2 w = *(const float2*)&fc1_w[k * 256 + c2 + gg * 64];
            #pragma unroll
            for (int i = 0; i < 4; i++) {
                h[i][gg].x += ar[i] * w.x; h[i][gg].y += ar[i] * w.y;
            }
        }
    }
    #define GELU1(v) v = 0.5f * v * (1.0f + erff(v * 0.70710678118f))
    #pragma unroll
    for (int i = 0; i < 4; i++)
        #pragma unroll
        for (int gg = 0; gg < 4; gg++) { GELU1(h[i][gg].x); GELU1(h[i][gg].y); }
    #undef GELU1
    #pragma unroll
    for (int gg = 0; gg < 4; gg++) {
        *(float4*)&Hid[c2 + gg * 64][r0] =
            make_float4(h[0][gg].x, h[1][gg].x, h[2][gg].x, h[3][gg].x);
        *(float4*)&Hid[c2 + 1 + gg * 64][r0] =
            make_float4(h[0][gg].y, h[1][gg].y, h[2][gg].y, h[3][gg].y);
    }
    __syncthreads();

    float2 ob = *(const float2*)&fc2_b[c2];
    float2 o[4] = {ob, ob, ob, ob};
    #pragma unroll 8
    for (int k = 0; k < 256; k++) {
        float4 aa = *(const float4*)&Hid[k][r0];
        float  ar[4] = {aa.x, aa.y, aa.z, aa.w};
        float2 w = *(const float2*)&fc2_w[k * 64 + c2];
        #pragma unroll
        for (int i = 0; i < 4; i++) {
            o[i].x += ar[i] * w.x; o[i].y += ar[i] * w.y;
        }
    }
    #pragma unroll
    for (int i = 0; i < 4; i++) {
        o[i].x += a[i].x; o[i].y += a[i].y;
        *(float2*)&out[(t0 + r0 + i) * 64 + c2] = o[i];
    }
}

extern "C" void kernel_launch(void* const* d_in, const int* in_sizes, int n_in,
                              void* d_out, int out_size, void* d_ws, size_t ws_size,
                              hipStream_t stream) {
    const float* x       = (const float*)d_in[0];
    const float* norm1_g = (const float*)d_in[1];
    const float* norm1_b = (const float*)d_in[2];
    const float* qkv_w   = (const float*)d_in[3];
    const float* qkv_b   = (const float*)d_in[4];
    const float* rpb     = (const float*)d_in[5];
    const float* proj_w  = (const float*)d_in[6];
    const float* proj_b  = (const float*)d_in[7];
    const float* norm2_g = (const float*)d_in[8];
    const float* norm2_b = (const float*)d_in[9];
    const float* fc1_w   = (const float*)d_in[10];
    const float* fc1_b   = (const float*)d_in[11];
    const float* fc2_w   = (const float*)d_in[12];
    const float* fc2_b   = (const float*)d_in[13];
    float* out = (float*)d_out;

    float* ws = (float*)d_ws;
    float* qkv      = ws;                      // 9216*192
    float* attn_out = qkv + NTOK * 192;        // 9216*64

    dim3 blk(256);
    // 1. qkv = LN1(x) @ qkv_w + qkv_b  (one block per tile, all 192 cols)
    ln_gemm_kernel<<<NTOK / 32, blk, 0, stream>>>(x, norm1_g, norm1_b, qkv_w, qkv_b, qkv);
    // 2. neighborhood attention (double-buffered LDS K/V; 4 tokens/block)
    na_attn_kernel<<<NTOK / 16, blk, 0, stream>>>(qkv, rpb, attn_out);
    // 3. out = fused MLP (v4: 32 tok/block, 256 thr, 4 rows x 2 cols)
    mlp_fused_kernel<<<NTOK / 32, blk, 0, stream>>>(attn_out, x, proj_w, proj_b,
                                                    norm2_g, norm2_b, fc1_w, fc1_b,
                                                    fc2_w, fc2_b, out);
}